// Round 6
// baseline (318.984 us; speedup 1.0000x reference)
//
#include <hip/hip_runtime.h>
#include <math.h>

#define N_REAL 2800
#define NPAD   3000
#define F_IN   8192
#define H1     256
#define H2     128
#define NE     179200
#define UDIM   512
#define NGATE  512
#define MPAD   3072
#define SPLITK 16
#define KCH    (F_IN / SPLITK)   // 512

typedef _Float16 half8_t __attribute__((ext_vector_type(8)));
typedef _Float16 half4_t __attribute__((ext_vector_type(4)));
typedef float    floatx4 __attribute__((ext_vector_type(4)));

__device__ __forceinline__ void async_g2l_16(const _Float16* g, _Float16* l) {
    __builtin_amdgcn_global_load_lds(
        (const __attribute__((address_space(1))) unsigned int*)g,
        (__attribute__((address_space(3))) unsigned int*)l, 16, 0, 0);
}

// ---------------- prep: wT transpose | Wc+biasv build | zero deg/counts ----------------
__global__ __launch_bounds__(256)
void prep_kernel(const float* __restrict__ w, const float* __restrict__ Wx,
                 const float* __restrict__ cw0, const float* __restrict__ cw1,
                 const float* __restrict__ bg, const float* __restrict__ cb,
                 _Float16* __restrict__ wT, _Float16* __restrict__ Wc,
                 float* __restrict__ biasv, float* __restrict__ deg,
                 int* __restrict__ counts) {
    int b = blockIdx.x;
    if (b < 2048) {
        __shared__ float tile[32][33];
        int k0 = (b & 255) * 32;
        int n0 = (b >> 8) * 32;
        int tx = threadIdx.x & 31, ty = threadIdx.x >> 5; // 32 x 8
#pragma unroll
        for (int r = 0; r < 4; r++)
            tile[ty + r * 8][tx] = w[(size_t)(k0 + ty + r * 8) * H1 + n0 + tx];
        __syncthreads();
#pragma unroll
        for (int r = 0; r < 4; r++)
            wT[(size_t)(n0 + ty + r * 8) * F_IN + k0 + tx] = (_Float16)tile[tx][ty + r * 8];
    } else if (b < 3072) {
        int idx = (b - 2048) * 256 + threadIdx.x;
        if (idx < UDIM * NGATE) {
            int col = idx >> 9;   // gate*128+o
            int f   = idx & 511;
            int g = col >> 7, o = col & 127;
            float v;
            if (f < H1)            v = Wx[((size_t)g * H1 + f) * H2 + o];
            else if (f < H1 + H2)  v = cw0[((size_t)g * H2 + (f - H1)) * H2 + o];
            else                   v = cw1[((size_t)g * H2 + (f - H1 - H2)) * H2 + o];
            Wc[idx] = (_Float16)v;
            if (f == 0) biasv[col] = bg[col] + cb[col];
        }
    } else {
        int i = (b - 3072) * 256 + threadIdx.x;   // 0..6143
        if (i < NPAD) deg[i] = 0.f;
        else { int j = i - NPAD; if (j < 3072) counts[j] = 0; }
    }
}

// ---------------- graph: histogram ----------------
__global__ void hist_kernel(const int* __restrict__ ei, const float* __restrict__ ew,
                            float* __restrict__ deg, int* __restrict__ counts) {
    int e = blockIdx.x * blockDim.x + threadIdx.x;
    if (e < NE) {
        int r = ei[e];
        int c = ei[NE + e];
        atomicAdd(&deg[r], ew[e]);
        atomicAdd(&counts[c], 1);
    }
}

// ---------------- GEMM1 (blocks 0..767) + scan (block 768) ----------------
__global__ __launch_bounds__(256, 3)
void gemm1_scan(const float* __restrict__ x, const _Float16* __restrict__ wT,
                float* __restrict__ P,
                const int* __restrict__ counts, int* __restrict__ offsets,
                const float* __restrict__ deg, float* __restrict__ dinv,
                int* __restrict__ cursor) {
    __shared__ __align__(16) _Float16 As[8][64][8];   // 8 KB
    __shared__ __align__(16) _Float16 Bs[8][256][8];  // 32 KB
    __shared__ int wsum[4];

    if (blockIdx.x == 768) {
        // ---- 256-thread shfl exclusive scan over counts[0..2999] + dinv ----
        int t = threadIdx.x, lane = t & 63, wv = t >> 6;
        int v[12]; int i0 = t * 12; int s = 0;
#pragma unroll
        for (int j = 0; j < 12; j++) { int i = i0 + j; v[j] = (i < NPAD) ? counts[i] : 0; s += v[j]; }
        int incl = s;
#pragma unroll
        for (int d = 1; d < 64; d <<= 1) { int nn = __shfl_up(incl, d); if (lane >= d) incl += nn; }
        if (lane == 63) wsum[wv] = incl;
        __syncthreads();
        int wbase = 0;
        for (int w = 0; w < wv; w++) wbase += wsum[w];
        int run = wbase + incl - s;
#pragma unroll
        for (int j = 0; j < 12; j++) {
            int i = i0 + j;
            if (i < NPAD) { offsets[i] = run; cursor[i] = run; run += v[j]; }
            else if (i == NPAD) offsets[i] = run;
        }
        for (int i = t; i < NPAD; i += 256) {
            float d = deg[i];
            dinv[i] = (d > 0.f) ? rsqrtf(d) : 0.f;
        }
        return;
    }

    const int t = threadIdx.x;
    const int wave = t >> 6, lane = t & 63;
    const int l16 = lane & 15, u4 = lane >> 4;
    const int b = blockIdx.x;
    const int m0 = (b % 48) * 64;
    const int kbase = (b / 48) * KCH;

    const int arow = t >> 2;      // 0..63
    const int aseg = t & 3;       // 0..3 (16 f32 each)
    const bool avalid = (m0 + arow) < N_REAL;
    const float* agp = x + (size_t)(m0 + arow) * F_IN + kbase + aseg * 16;

    floatx4 acc[4][4] = {};

    float4 a0 = make_float4(0.f, 0.f, 0.f, 0.f), a1 = a0, a2 = a0, a3 = a0;
    if (avalid) {
        a0 = *(const float4*)(agp + 0);
        a1 = *(const float4*)(agp + 4);
        a2 = *(const float4*)(agp + 8);
        a3 = *(const float4*)(agp + 12);
    }

    for (int kk = 0; kk < KCH; kk += 64) {
#pragma unroll
        for (int q = 0; q < 2; q++) {
            int u = wave * 2 + q;
            const _Float16* bsrc = wT + kbase + kk + u * 8;
#pragma unroll
            for (int rg = 0; rg < 4; rg++)
                async_g2l_16(bsrc + (size_t)(rg * 64 + lane) * F_IN, &Bs[u][rg * 64 + lane][0]);
        }
        half8_t hlo, hhi;
        hlo[0] = (_Float16)a0.x; hlo[1] = (_Float16)a0.y; hlo[2] = (_Float16)a0.z; hlo[3] = (_Float16)a0.w;
        hlo[4] = (_Float16)a1.x; hlo[5] = (_Float16)a1.y; hlo[6] = (_Float16)a1.z; hlo[7] = (_Float16)a1.w;
        hhi[0] = (_Float16)a2.x; hhi[1] = (_Float16)a2.y; hhi[2] = (_Float16)a2.z; hhi[3] = (_Float16)a2.w;
        hhi[4] = (_Float16)a3.x; hhi[5] = (_Float16)a3.y; hhi[6] = (_Float16)a3.z; hhi[7] = (_Float16)a3.w;
        *(half8_t*)&As[aseg * 2][arow][0]     = hlo;
        *(half8_t*)&As[aseg * 2 + 1][arow][0] = hhi;
        __syncthreads();
        // prefetch next x chunk into registers (overlaps MFMA phase)
        if (kk + 64 < KCH && avalid) {
            a0 = *(const float4*)(agp + kk + 64);
            a1 = *(const float4*)(agp + kk + 68);
            a2 = *(const float4*)(agp + kk + 72);
            a3 = *(const float4*)(agp + kk + 76);
        }
#pragma unroll
        for (int ks = 0; ks < 2; ks++) {
            half8_t a[4], bfr[4];
#pragma unroll
            for (int i = 0; i < 4; i++) a[i] = *(const half8_t*)&As[ks * 4 + u4][i * 16 + l16][0];
#pragma unroll
            for (int j = 0; j < 4; j++) bfr[j] = *(const half8_t*)&Bs[ks * 4 + u4][wave * 64 + j * 16 + l16][0];
#pragma unroll
            for (int i = 0; i < 4; i++)
#pragma unroll
                for (int j = 0; j < 4; j++)
                    acc[i][j] = __builtin_amdgcn_mfma_f32_16x16x32_f16(a[i], bfr[j], acc[i][j], 0, 0, 0);
        }
        __syncthreads();
    }

    float* Pb = P + ((size_t)(b / 48) * MPAD + m0) * H1;
#pragma unroll
    for (int i = 0; i < 4; i++)
#pragma unroll
        for (int j = 0; j < 4; j++) {
            int n = wave * 64 + j * 16 + l16;
#pragma unroll
            for (int r = 0; r < 4; r++)
                Pb[(size_t)(i * 16 + u4 * 4 + r) * H1 + n] = acc[i][j][r];
        }
}

// ---------------- CSR scatter ----------------
__global__ void scatter_kernel(const int* __restrict__ ei, int* __restrict__ cursor,
                               int* __restrict__ eid) {
    int e = blockIdx.x * blockDim.x + threadIdx.x;
    if (e < NE) {
        int c = ei[NE + e];
        int p = atomicAdd(&cursor[c], 1);
        eid[p] = e;
    }
}

// ---------------- fused: T1 gather (ILP-8) | P-reduce+relu->z | h0 copy -> U16 ----------------
#define ZBLK 1536
#define HBLK 768
__global__ __launch_bounds__(128)
void t1epi_kernel(const int* __restrict__ ei, const float* __restrict__ ew,
                  const float* __restrict__ h0, const float* __restrict__ dinv,
                  const int* __restrict__ offsets, const int* __restrict__ eid,
                  const float* __restrict__ P, const float* __restrict__ fc0_b,
                  _Float16* __restrict__ U16) {
    int b = blockIdx.x;
    int t = threadIdx.x;
    if (b < NPAD) {
        __shared__ int   sr[128];
        __shared__ float sw[128];
        int n = b;
        int beg = offsets[n], end = offsets[n + 1];
        float dc = dinv[n];
        float acc = 0.f;
        for (int base = beg; base < end; base += 128) {
            int j = base + t;
            if (j < end) {
                int e = eid[j];
                int r = ei[e];
                sr[t] = r;
                sw[t] = -dinv[r] * ew[e];
            }
            __syncthreads();
            int cnt = min(128, end - base);
            int k = 0;
            for (; k + 8 <= cnt; k += 8) {
                int   r0 = sr[k],   r1 = sr[k+1], r2 = sr[k+2], r3 = sr[k+3];
                int   r4 = sr[k+4], r5 = sr[k+5], r6 = sr[k+6], r7 = sr[k+7];
                float w0 = sw[k],   w1 = sw[k+1], w2 = sw[k+2], w3 = sw[k+3];
                float w4 = sw[k+4], w5 = sw[k+5], w6 = sw[k+6], w7 = sw[k+7];
                float v0 = h0[(size_t)r0 * H2 + t];
                float v1 = h0[(size_t)r1 * H2 + t];
                float v2 = h0[(size_t)r2 * H2 + t];
                float v3 = h0[(size_t)r3 * H2 + t];
                float v4 = h0[(size_t)r4 * H2 + t];
                float v5 = h0[(size_t)r5 * H2 + t];
                float v6 = h0[(size_t)r6 * H2 + t];
                float v7 = h0[(size_t)r7 * H2 + t];
                acc += w0 * v0 + w1 * v1 + w2 * v2 + w3 * v3
                     + w4 * v4 + w5 * v5 + w6 * v6 + w7 * v7;
            }
            for (; k < cnt; k++)
                acc += sw[k] * h0[(size_t)sr[k] * H2 + t];
            __syncthreads();
        }
        U16[(size_t)n * UDIM + H1 + H2 + t] = (_Float16)(acc * dc);
    } else if (b < NPAD + ZBLK) {
        int q = (b - NPAD) * 128 + t;
        int m = q >> 6;
        int n4 = (q & 63) * 4;
        float s0 = 0.f, s1 = 0.f, s2 = 0.f, s3 = 0.f;
#pragma unroll
        for (int sk = 0; sk < SPLITK; sk++) {
            float4 p = *(const float4*)&P[((size_t)sk * MPAD + m) * H1 + n4];
            s0 += p.x; s1 += p.y; s2 += p.z; s3 += p.w;
        }
        float4 bb = *(const float4*)&fc0_b[n4];
        half4_t h;
        h[0] = (_Float16)fmaxf(s0 + bb.x, 0.f);
        h[1] = (_Float16)fmaxf(s1 + bb.y, 0.f);
        h[2] = (_Float16)fmaxf(s2 + bb.z, 0.f);
        h[3] = (_Float16)fmaxf(s3 + bb.w, 0.f);
        *(half4_t*)&U16[(size_t)m * UDIM + n4] = h;
    } else {
        int q = (b - NPAD - ZBLK) * 128 + t;
        int m = q >> 5;
        int o4 = (q & 31) * 4;
        half4_t h = {};
        if (m < NPAD) {
            float4 v = *(const float4*)&h0[(size_t)m * H2 + o4];
            h[0] = (_Float16)v.x; h[1] = (_Float16)v.y; h[2] = (_Float16)v.z; h[3] = (_Float16)v.w;
        }
        *(half4_t*)&U16[(size_t)m * UDIM + H1 + o4] = h;
    }
}

// ---------------- fused GEMM2 + LSTM + projection ----------------
// 48 blocks x 256 thr; tile m=64, n=512 (all gates). Wave w covers o-cols
// [w*32, w*32+32) of ALL 4 gates -> LSTM is wave-local; projection via
// shfl(l16) + LDS cross-wave reduce.
__global__ __launch_bounds__(256, 1)
void gemm2lstm(const _Float16* __restrict__ U16, const _Float16* __restrict__ Wc,
               const float* __restrict__ biasv, const float* __restrict__ c0,
               const float* __restrict__ fc_w, const float* __restrict__ fc_b,
               float* __restrict__ out) {
    __shared__ __align__(16) _Float16 As[4][64][8];    // 4 KB
    __shared__ __align__(16) _Float16 Bs[4][512][8];   // 32 KB
    __shared__ float rowsum[4][64];                    // 1 KB
    const int t = threadIdx.x;
    const int wave = t >> 6, lane = t & 63;
    const int l16 = lane & 15, u4 = lane >> 4;
    const int m0 = blockIdx.x * 64;

    floatx4 acc[4][8] = {};   // [m-tile][g*2+h]

    for (int kk = 0; kk < UDIM; kk += 32) {
        async_g2l_16(U16 + (size_t)(m0 + lane) * UDIM + kk + wave * 8, &As[wave][lane][0]);
#pragma unroll
        for (int rg = 0; rg < 8; rg++)
            async_g2l_16(Wc + (size_t)(rg * 64 + lane) * UDIM + kk + wave * 8,
                         &Bs[wave][rg * 64 + lane][0]);
        __syncthreads();
        half8_t a[4], bfr[8];
#pragma unroll
        for (int i = 0; i < 4; i++) a[i] = *(const half8_t*)&As[u4][i * 16 + l16][0];
#pragma unroll
        for (int j = 0; j < 8; j++) {
            int g = j >> 1, h = j & 1;
            int n = g * 128 + wave * 32 + h * 16 + l16;
            bfr[j] = *(const half8_t*)&Bs[u4][n][0];
        }
#pragma unroll
        for (int i = 0; i < 4; i++)
#pragma unroll
            for (int j = 0; j < 8; j++)
                acc[i][j] = __builtin_amdgcn_mfma_f32_16x16x32_f16(a[i], bfr[j], acc[i][j], 0, 0, 0);
        __syncthreads();
    }

    float bI[2], bF[2], bT[2], bO[2], fw[2];
#pragma unroll
    for (int h = 0; h < 2; h++) {
        int o = wave * 32 + h * 16 + l16;
        bI[h] = biasv[o];       bF[h] = biasv[128 + o];
        bT[h] = biasv[256 + o]; bO[h] = biasv[384 + o];
        fw[h] = fc_w[o];
    }
#pragma unroll
    for (int i = 0; i < 4; i++) {
#pragma unroll
        for (int r = 0; r < 4; r++) {
            int m = m0 + i * 16 + u4 * 4 + r;
            float pr = 0.f;
#pragma unroll
            for (int h = 0; h < 2; h++) {
                int o = wave * 32 + h * 16 + l16;
                float gi = acc[i][0 + h][r] + bI[h];
                float gf = acc[i][2 + h][r] + bF[h];
                float gt = acc[i][4 + h][r] + bT[h];
                float go = acc[i][6 + h][r] + bO[h];
                float iv = 1.f / (1.f + expf(-gi));
                float fv = 1.f / (1.f + expf(-gf));
                float tv = tanhf(gt);
                float ov = 1.f / (1.f + expf(-go));
                float cold = (m < NPAD) ? c0[(size_t)m * H2 + o] : 0.f;
                float c = fv * cold + iv * tv;
                float hn = ov * tanhf(c);
                if (m < NPAD) out[N_REAL + (size_t)m * H2 + o] = hn;
                pr += fmaxf(hn, 0.f) * fw[h];
            }
#pragma unroll
            for (int d = 1; d < 16; d <<= 1) pr += __shfl_xor(pr, d);
            if (l16 == 0) rowsum[wave][i * 16 + u4 * 4 + r] = pr;
        }
    }
    __syncthreads();
    if (t < 64) {
        int m = m0 + t;
        if (m < N_REAL)
            out[m] = rowsum[0][t] + rowsum[1][t] + rowsum[2][t] + rowsum[3][t] + fc_b[0];
    }
}

extern "C" void kernel_launch(void* const* d_in, const int* in_sizes, int n_in,
                              void* d_out, int out_size, void* d_ws, size_t ws_size,
                              hipStream_t stream) {
    const float* x     = (const float*)d_in[0];
    const int*   ei    = (const int*)d_in[1];
    const float* ew    = (const float*)d_in[2];
    const float* h0    = (const float*)d_in[3];
    const float* c0    = (const float*)d_in[4];
    const float* fc0_w = (const float*)d_in[5];
    const float* fc0_b = (const float*)d_in[6];
    const float* Wx    = (const float*)d_in[7];
    const float* bg    = (const float*)d_in[8];
    const float* cw0   = (const float*)d_in[9];
    const float* cw1   = (const float*)d_in[10];
    const float* cb    = (const float*)d_in[11];
    const float* fc_w  = (const float*)d_in[12];
    const float* fc_b  = (const float*)d_in[13];
    float* out = (float*)d_out;

    float* P      = (float*)d_ws;                     // 16*3072*256 f32 = 50.3 MB
    float* biasv  = P + (size_t)SPLITK * MPAD * H1;   // 512
    float* deg    = biasv + NGATE;                    // 3000
    float* dinv   = deg + NPAD;                       // 3000
    int*   counts = (int*)(dinv + NPAD);              // 3072
    int*   offs   = counts + 3072;                    // 3072 (need 3001)
    int*   cursor = offs + 3072;                      // 3072
    int*   eid    = cursor + 3072;                    // NE
    _Float16* U16 = (_Float16*)(((uintptr_t)(eid + NE) + 255) & ~(uintptr_t)255); // 3072*512
    _Float16* Wc  = U16 + (size_t)MPAD * UDIM;        // 512*512
    _Float16* wT  = Wc + (size_t)UDIM * NGATE;        // 256*8192

    prep_kernel<<<3096, 256, 0, stream>>>(fc0_w, Wx, cw0, cw1, bg, cb, wT, Wc, biasv, deg, counts);
    hist_kernel<<<(NE + 255) / 256, 256, 0, stream>>>(ei, ew, deg, counts);
    gemm1_scan<<<769, 256, 0, stream>>>(x, wT, P, counts, offs, deg, dinv, cursor);
    scatter_kernel<<<(NE + 255) / 256, 256, 0, stream>>>(ei, cursor, eid);
    t1epi_kernel<<<NPAD + ZBLK + HBLK, 128, 0, stream>>>(ei, ew, h0, dinv, offs, eid, P, fc0_b, U16);
    gemm2lstm<<<48, 256, 0, stream>>>(U16, Wc, biasv, c0, fc_w, fc_b, out);
}

// Round 7
// 275.655 us; speedup vs baseline: 1.1572x; 1.1572x over previous
//
#include <hip/hip_runtime.h>
#include <math.h>

#define N_REAL 2800
#define NPAD   3000
#define F_IN   8192
#define H1     256
#define H2     128
#define NE     179200
#define UDIM   512
#define NGATE  512
#define MPAD   3072
#define SPLITK 16
#define KCH    (F_IN / SPLITK)   // 512

typedef _Float16 half8_t __attribute__((ext_vector_type(8)));
typedef _Float16 half4_t __attribute__((ext_vector_type(4)));
typedef float    floatx4 __attribute__((ext_vector_type(4)));

__device__ __forceinline__ void async_g2l_16(const _Float16* g, _Float16* l) {
    __builtin_amdgcn_global_load_lds(
        (const __attribute__((address_space(1))) unsigned int*)g,
        (__attribute__((address_space(3))) unsigned int*)l, 16, 0, 0);
}

// ---------------- prep: fc0_w -> wTp[k/8][n][8] | Wcp[f/8][col][8] + biasv | zero deg/counts ----
// wTp unit layout == gemm1 LDS tile layout -> staging loads are lane-contiguous (coalesced).
__global__ __launch_bounds__(256)
void prep_kernel(const float* __restrict__ w, const float* __restrict__ Wx,
                 const float* __restrict__ cw0, const float* __restrict__ cw1,
                 const float* __restrict__ bg, const float* __restrict__ cb,
                 _Float16* __restrict__ wTp, _Float16* __restrict__ Wcp,
                 float* __restrict__ biasv, float* __restrict__ deg,
                 int* __restrict__ counts) {
    int b = blockIdx.x;
    if (b < 2048) {
        __shared__ float tile[32][33];
        int k0 = (b & 255) * 32;
        int n0 = (b >> 8) * 32;
        int tx = threadIdx.x & 31, ty = threadIdx.x >> 5; // 32 x 8
#pragma unroll
        for (int r = 0; r < 4; r++)
            tile[ty + r * 8][tx] = w[(size_t)(k0 + ty + r * 8) * H1 + n0 + tx];
        __syncthreads();
        int t = threadIdx.x;
        if (t < 128) {
            int u_l = t >> 5;        // k-unit 0..3
            int n_l = t & 31;        // col 0..31
            half8_t h;
#pragma unroll
            for (int j = 0; j < 8; j++) h[j] = (_Float16)tile[u_l * 8 + j][n_l];
            *(half8_t*)&wTp[(((size_t)(k0 >> 3) + u_l) * H1 + n0 + n_l) * 8] = h;
        }
    } else if (b < 3072) {
        int idx = (b - 2048) * 256 + threadIdx.x;
        if (idx < UDIM * NGATE) {
            int col = idx >> 9;   // gate*128+o
            int f   = idx & 511;
            int g = col >> 7, o = col & 127;
            float v;
            if (f < H1)            v = Wx[((size_t)g * H1 + f) * H2 + o];
            else if (f < H1 + H2)  v = cw0[((size_t)g * H2 + (f - H1)) * H2 + o];
            else                   v = cw1[((size_t)g * H2 + (f - H1 - H2)) * H2 + o];
            Wcp[(((size_t)(f >> 3)) * NGATE + col) * 8 + (f & 7)] = (_Float16)v;
            if (f == 0) biasv[col] = bg[col] + cb[col];
        }
    } else {
        int i = (b - 3072) * 256 + threadIdx.x;   // 0..6143
        if (i < NPAD) deg[i] = 0.f;
        else { int j = i - NPAD; if (j < 3072) counts[j] = 0; }
    }
}

// ---------------- GEMM1: P[sk] = x(f32->f16) @ W, tile 64x256, K=64/iter, coalesced B staging ----
__global__ __launch_bounds__(256, 3)
void gemm1_fused(const float* __restrict__ x, const _Float16* __restrict__ wTp,
                 float* __restrict__ P) {
    __shared__ __align__(16) _Float16 As[8][64][8];   // 8 KB
    __shared__ __align__(16) _Float16 Bs[8][256][8];  // 32 KB
    const int t = threadIdx.x;
    const int wave = t >> 6, lane = t & 63;
    const int l16 = lane & 15, u4 = lane >> 4;
    const int m0 = blockIdx.x * 64;
    const int kbase = blockIdx.y * KCH;

    const int arow = t >> 2;      // 0..63
    const int aseg = t & 3;       // 0..3 (16 f32 each)
    const bool avalid = (m0 + arow) < N_REAL;
    const float* agp = x + (size_t)(m0 + arow) * F_IN + kbase + aseg * 16;

    floatx4 acc[4][4] = {};

    float4 a0 = make_float4(0.f, 0.f, 0.f, 0.f), a1 = a0, a2 = a0, a3 = a0;
    if (avalid) {
        a0 = *(const float4*)(agp + 0);
        a1 = *(const float4*)(agp + 4);
        a2 = *(const float4*)(agp + 8);
        a3 = *(const float4*)(agp + 12);
    }

    for (int kk = 0; kk < KCH; kk += 64) {
        // B: coalesced — consecutive lanes fetch consecutive 16-B units
        const _Float16* bbase = wTp + ((size_t)((kbase + kk) >> 3)) * (H1 * 8);
#pragma unroll
        for (int q = 0; q < 2; q++) {
            int u = wave * 2 + q;
#pragma unroll
            for (int rg = 0; rg < 4; rg++)
                async_g2l_16(bbase + ((size_t)u * H1 + rg * 64 + lane) * 8,
                             &Bs[u][rg * 64 + lane][0]);
        }
        half8_t hlo, hhi;
        hlo[0] = (_Float16)a0.x; hlo[1] = (_Float16)a0.y; hlo[2] = (_Float16)a0.z; hlo[3] = (_Float16)a0.w;
        hlo[4] = (_Float16)a1.x; hlo[5] = (_Float16)a1.y; hlo[6] = (_Float16)a1.z; hlo[7] = (_Float16)a1.w;
        hhi[0] = (_Float16)a2.x; hhi[1] = (_Float16)a2.y; hhi[2] = (_Float16)a2.z; hhi[3] = (_Float16)a2.w;
        hhi[4] = (_Float16)a3.x; hhi[5] = (_Float16)a3.y; hhi[6] = (_Float16)a3.z; hhi[7] = (_Float16)a3.w;
        *(half8_t*)&As[aseg * 2][arow][0]     = hlo;
        *(half8_t*)&As[aseg * 2 + 1][arow][0] = hhi;
        __syncthreads();
        // prefetch next x chunk into registers (overlaps MFMA phase)
        if (kk + 64 < KCH && avalid) {
            a0 = *(const float4*)(agp + kk + 64);
            a1 = *(const float4*)(agp + kk + 68);
            a2 = *(const float4*)(agp + kk + 72);
            a3 = *(const float4*)(agp + kk + 76);
        }
#pragma unroll
        for (int ks = 0; ks < 2; ks++) {
            half8_t a[4], bfr[4];
#pragma unroll
            for (int i = 0; i < 4; i++) a[i] = *(const half8_t*)&As[ks * 4 + u4][i * 16 + l16][0];
#pragma unroll
            for (int j = 0; j < 4; j++) bfr[j] = *(const half8_t*)&Bs[ks * 4 + u4][wave * 64 + j * 16 + l16][0];
#pragma unroll
            for (int i = 0; i < 4; i++)
#pragma unroll
                for (int j = 0; j < 4; j++)
                    acc[i][j] = __builtin_amdgcn_mfma_f32_16x16x32_f16(a[i], bfr[j], acc[i][j], 0, 0, 0);
        }
        __syncthreads();
    }

    float* Pb = P + ((size_t)blockIdx.y * MPAD + m0) * H1;
#pragma unroll
    for (int i = 0; i < 4; i++)
#pragma unroll
        for (int j = 0; j < 4; j++) {
            int n = wave * 64 + j * 16 + l16;
#pragma unroll
            for (int r = 0; r < 4; r++)
                Pb[(size_t)(i * 16 + u4 * 4 + r) * H1 + n] = acc[i][j][r];
        }
}

// ---------------- graph: histogram ----------------
__global__ void hist_kernel(const int* __restrict__ ei, const float* __restrict__ ew,
                            float* __restrict__ deg, int* __restrict__ counts) {
    int e = blockIdx.x * blockDim.x + threadIdx.x;
    if (e < NE) {
        int r = ei[e];
        int c = ei[NE + e];
        atomicAdd(&deg[r], ew[e]);
        atomicAdd(&counts[c], 1);
    }
}

// ---------------- scan: shfl exclusive scan + dinv + cursor (1 block) ----------------
__global__ __launch_bounds__(1024)
void scan_kernel(const int* __restrict__ counts, int* __restrict__ offsets,
                 const float* __restrict__ deg, float* __restrict__ dinv,
                 int* __restrict__ cursor) {
    __shared__ int wt[16];
    int t = threadIdx.x;
    int i0 = t * 3;
    int v0 = (i0     < NPAD) ? counts[i0]     : 0;
    int v1 = (i0 + 1 < NPAD) ? counts[i0 + 1] : 0;
    int v2 = (i0 + 2 < NPAD) ? counts[i0 + 2] : 0;
    int s = v0 + v1 + v2;
    int incl = s;
#pragma unroll
    for (int d = 1; d < 64; d <<= 1) {
        int n = __shfl_up(incl, d);
        if ((t & 63) >= d) incl += n;
    }
    if ((t & 63) == 63) wt[t >> 6] = incl;
    __syncthreads();
    if (t < 64) {
        int w = (t < 16) ? wt[t] : 0;
        int wi = w;
#pragma unroll
        for (int d = 1; d < 16; d <<= 1) {
            int n = __shfl_up(wi, d);
            if (t >= d) wi += n;
        }
        if (t < 16) wt[t] = wi - w;
    }
    __syncthreads();
    int base = wt[t >> 6] + (incl - s);
    if (i0 <= NPAD)     { offsets[i0] = base;               if (i0     < NPAD) cursor[i0]     = base; }
    if (i0 + 1 <= NPAD) { offsets[i0 + 1] = base + v0;      if (i0 + 1 < NPAD) cursor[i0 + 1] = base + v0; }
    if (i0 + 2 <= NPAD) { offsets[i0 + 2] = base + v0 + v1; if (i0 + 2 < NPAD) cursor[i0 + 2] = base + v0 + v1; }
    for (int i = t; i < NPAD; i += 1024) {
        float d = deg[i];
        dinv[i] = (d > 0.f) ? rsqrtf(d) : 0.f;
    }
}

// ---------------- CSR scatter ----------------
__global__ void scatter_kernel(const int* __restrict__ ei, int* __restrict__ cursor,
                               int* __restrict__ eid) {
    int e = blockIdx.x * blockDim.x + threadIdx.x;
    if (e < NE) {
        int c = ei[NE + e];
        int p = atomicAdd(&cursor[c], 1);
        eid[p] = e;
    }
}

// ---------------- fused: T1 gather (ILP-8) | P-reduce+relu->z | h0 copy -> U16 ----------------
#define ZBLK 1536
#define HBLK 768
__global__ __launch_bounds__(128)
void t1epi_kernel(const int* __restrict__ ei, const float* __restrict__ ew,
                  const float* __restrict__ h0, const float* __restrict__ dinv,
                  const int* __restrict__ offsets, const int* __restrict__ eid,
                  const float* __restrict__ P, const float* __restrict__ fc0_b,
                  _Float16* __restrict__ U16) {
    int b = blockIdx.x;
    int t = threadIdx.x;
    if (b < NPAD) {
        __shared__ int   sr[128];
        __shared__ float sw[128];
        int n = b;
        int beg = offsets[n], end = offsets[n + 1];
        float dc = dinv[n];
        float acc = 0.f;
        for (int base = beg; base < end; base += 128) {
            int j = base + t;
            if (j < end) {
                int e = eid[j];
                int r = ei[e];
                sr[t] = r;
                sw[t] = -dinv[r] * ew[e];
            }
            __syncthreads();
            int cnt = min(128, end - base);
            int k = 0;
            for (; k + 8 <= cnt; k += 8) {
                int   r0 = sr[k],   r1 = sr[k+1], r2 = sr[k+2], r3 = sr[k+3];
                int   r4 = sr[k+4], r5 = sr[k+5], r6 = sr[k+6], r7 = sr[k+7];
                float w0 = sw[k],   w1 = sw[k+1], w2 = sw[k+2], w3 = sw[k+3];
                float w4 = sw[k+4], w5 = sw[k+5], w6 = sw[k+6], w7 = sw[k+7];
                float v0 = h0[(size_t)r0 * H2 + t];
                float v1 = h0[(size_t)r1 * H2 + t];
                float v2 = h0[(size_t)r2 * H2 + t];
                float v3 = h0[(size_t)r3 * H2 + t];
                float v4 = h0[(size_t)r4 * H2 + t];
                float v5 = h0[(size_t)r5 * H2 + t];
                float v6 = h0[(size_t)r6 * H2 + t];
                float v7 = h0[(size_t)r7 * H2 + t];
                acc += w0 * v0 + w1 * v1 + w2 * v2 + w3 * v3
                     + w4 * v4 + w5 * v5 + w6 * v6 + w7 * v7;
            }
            for (; k < cnt; k++)
                acc += sw[k] * h0[(size_t)sr[k] * H2 + t];
            __syncthreads();
        }
        U16[(size_t)n * UDIM + H1 + H2 + t] = (_Float16)(acc * dc);
    } else if (b < NPAD + ZBLK) {
        int q = (b - NPAD) * 128 + t;
        int m = q >> 6;
        int n4 = (q & 63) * 4;
        float s0 = 0.f, s1 = 0.f, s2 = 0.f, s3 = 0.f;
#pragma unroll
        for (int sk = 0; sk < SPLITK; sk++) {
            float4 p = *(const float4*)&P[((size_t)sk * MPAD + m) * H1 + n4];
            s0 += p.x; s1 += p.y; s2 += p.z; s3 += p.w;
        }
        float4 bb = *(const float4*)&fc0_b[n4];
        half4_t h;
        h[0] = (_Float16)fmaxf(s0 + bb.x, 0.f);
        h[1] = (_Float16)fmaxf(s1 + bb.y, 0.f);
        h[2] = (_Float16)fmaxf(s2 + bb.z, 0.f);
        h[3] = (_Float16)fmaxf(s3 + bb.w, 0.f);
        *(half4_t*)&U16[(size_t)m * UDIM + n4] = h;
    } else {
        int q = (b - NPAD - ZBLK) * 128 + t;
        int m = q >> 5;
        int o4 = (q & 31) * 4;
        half4_t h = {};
        if (m < NPAD) {
            float4 v = *(const float4*)&h0[(size_t)m * H2 + o4];
            h[0] = (_Float16)v.x; h[1] = (_Float16)v.y; h[2] = (_Float16)v.z; h[3] = (_Float16)v.w;
        }
        *(half4_t*)&U16[(size_t)m * UDIM + H1 + o4] = h;
    }
}

// ---------------- GEMM2 (MFMA f16, split-K=2, coalesced B staging): gatesP[z] = U16 @ W slice ----
__global__ __launch_bounds__(256, 3)
void gemm2_mfma(const _Float16* __restrict__ U16, const _Float16* __restrict__ Wcp,
                float* __restrict__ gatesP) {
    __shared__ __align__(16) _Float16 As[8][64][8];
    __shared__ __align__(16) _Float16 Bs[8][256][8];
    const int t = threadIdx.x;
    const int wave = t >> 6, lane = t & 63;
    const int l16 = lane & 15, u4 = lane >> 4;
    const int n0 = blockIdx.x * 256;
    const int m0 = blockIdx.y * 64;
    const int kz = blockIdx.z * 256;

    floatx4 acc[4][4] = {};

    for (int kk = kz; kk < kz + 256; kk += 64) {
        const _Float16* bbase = Wcp + ((size_t)(kk >> 3)) * (NGATE * 8);
#pragma unroll
        for (int q = 0; q < 2; q++) {
            int u = wave * 2 + q;
            async_g2l_16(U16 + (size_t)(m0 + lane) * UDIM + kk + u * 8, &As[u][lane][0]);
#pragma unroll
            for (int rg = 0; rg < 4; rg++)
                async_g2l_16(bbase + ((size_t)u * NGATE + n0 + rg * 64 + lane) * 8,
                             &Bs[u][rg * 64 + lane][0]);
        }
        __syncthreads();
#pragma unroll
        for (int ks = 0; ks < 2; ks++) {
            half8_t a[4], bfr[4];
#pragma unroll
            for (int i = 0; i < 4; i++) a[i] = *(const half8_t*)&As[ks * 4 + u4][i * 16 + l16][0];
#pragma unroll
            for (int j = 0; j < 4; j++) bfr[j] = *(const half8_t*)&Bs[ks * 4 + u4][wave * 64 + j * 16 + l16][0];
#pragma unroll
            for (int i = 0; i < 4; i++)
#pragma unroll
                for (int j = 0; j < 4; j++)
                    acc[i][j] = __builtin_amdgcn_mfma_f32_16x16x32_f16(a[i], bfr[j], acc[i][j], 0, 0, 0);
        }
        __syncthreads();
    }

    float* g = gatesP + (size_t)blockIdx.z * MPAD * NGATE;
#pragma unroll
    for (int i = 0; i < 4; i++)
#pragma unroll
        for (int j = 0; j < 4; j++) {
            int n = n0 + wave * 64 + j * 16 + l16;
#pragma unroll
            for (int r = 0; r < 4; r++)
                g[(size_t)(m0 + i * 16 + u4 * 4 + r) * NGATE + n] = acc[i][j][r];
        }
}

// ---------------- LSTM elementwise + bias + output projection ----------------
__global__ __launch_bounds__(128)
void lstm_kernel(const float* __restrict__ gates, const float* __restrict__ c0,
                 const float* __restrict__ biasv, const float* __restrict__ fc_w,
                 const float* __restrict__ fc_b, float* __restrict__ out) {
    __shared__ float red[2];
    int n = blockIdx.x;
    int o = threadIdx.x;
    const float* g0 = gates + (size_t)n * NGATE;
    const float* g1 = g0 + (size_t)MPAD * NGATE;
    float gi = g0[o]          + g1[o]          + biasv[o];
    float gf = g0[H2 + o]     + g1[H2 + o]     + biasv[H2 + o];
    float gt = g0[2 * H2 + o] + g1[2 * H2 + o] + biasv[2 * H2 + o];
    float go = g0[3 * H2 + o] + g1[3 * H2 + o] + biasv[3 * H2 + o];
    float iv = 1.f / (1.f + expf(-gi));
    float fv = 1.f / (1.f + expf(-gf));
    float tv = tanhf(gt);
    float ov = 1.f / (1.f + expf(-go));
    float c = fv * c0[(size_t)n * H2 + o] + iv * tv;
    float h = ov * tanhf(c);
    out[N_REAL + (size_t)n * H2 + o] = h;

    float r = fmaxf(h, 0.f) * fc_w[o];
#pragma unroll
    for (int s = 32; s; s >>= 1) r += __shfl_down(r, s);
    if ((o & 63) == 0) red[o >> 6] = r;
    __syncthreads();
    if (o == 0 && n < N_REAL) out[n] = red[0] + red[1] + fc_b[0];
}

extern "C" void kernel_launch(void* const* d_in, const int* in_sizes, int n_in,
                              void* d_out, int out_size, void* d_ws, size_t ws_size,
                              hipStream_t stream) {
    const float* x     = (const float*)d_in[0];
    const int*   ei    = (const int*)d_in[1];
    const float* ew    = (const float*)d_in[2];
    const float* h0    = (const float*)d_in[3];
    const float* c0    = (const float*)d_in[4];
    const float* fc0_w = (const float*)d_in[5];
    const float* fc0_b = (const float*)d_in[6];
    const float* Wx    = (const float*)d_in[7];
    const float* bg    = (const float*)d_in[8];
    const float* cw0   = (const float*)d_in[9];
    const float* cw1   = (const float*)d_in[10];
    const float* cb    = (const float*)d_in[11];
    const float* fc_w  = (const float*)d_in[12];
    const float* fc_b  = (const float*)d_in[13];
    float* out = (float*)d_out;

    float* P      = (float*)d_ws;                     // 16*3072*256 f32 = 50.3 MB
    float* gates  = P + (size_t)SPLITK * MPAD * H1;   // 2*3072*512 f32
    float* biasv  = gates + 2 * (size_t)MPAD * NGATE; // 512
    float* deg    = biasv + NGATE;                    // 3000
    float* dinv   = deg + NPAD;                       // 3000
    int*   counts = (int*)(dinv + NPAD);              // 3072
    int*   offs   = counts + 3072;                    // 3072 (need 3001)
    int*   cursor = offs + 3072;                      // 3072
    int*   eid    = cursor + 3072;                    // NE
    _Float16* U16 = (_Float16*)(((uintptr_t)(eid + NE) + 255) & ~(uintptr_t)255); // 3072*512
    _Float16* Wcp = U16 + (size_t)MPAD * UDIM;        // 512*512
    _Float16* wTp = Wcp + (size_t)UDIM * NGATE;       // 256*8192

    prep_kernel<<<3096, 256, 0, stream>>>(fc0_w, Wx, cw0, cw1, bg, cb, wTp, Wcp, biasv, deg, counts);
    gemm1_fused<<<dim3(MPAD / 64, SPLITK), 256, 0, stream>>>(x, wTp, P);
    hist_kernel<<<(NE + 255) / 256, 256, 0, stream>>>(ei, ew, deg, counts);
    scan_kernel<<<1, 1024, 0, stream>>>(counts, offs, deg, dinv, cursor);
    scatter_kernel<<<(NE + 255) / 256, 256, 0, stream>>>(ei, cursor, eid);
    t1epi_kernel<<<NPAD + ZBLK + HBLK, 128, 0, stream>>>(ei, ew, h0, dinv, offs, eid, P, fc0_b, U16);
    gemm2_mfma<<<dim3(NGATE / 256, MPAD / 64, 2), 256, 0, stream>>>(U16, Wcp, gates);
    lstm_kernel<<<NPAD, 128, 0, stream>>>(gates, c0, biasv, fc_w, fc_b, out);
}